// Round 3
// baseline (385.360 us; speedup 1.0000x reference)
//
#include <hip/hip_runtime.h>
#include <hip/hip_bf16.h>

// ---------------------------------------------------------------------------
// T5 MHA: B=2, S=2048, D_FF=1024, H=16, DK=64, INNER=1024
// QK^T path at ~fp24 via bf16 hi+lo splits (3-chain MFMA). V path plain bf16.
// Attn v2: swapped-operand S^T layout, no staging LDS, no barriers:
//   - K/V frags direct from global (V pre-transposed [B,H,DK,S] by its GEMM)
//   - mask added via float4 loads (kv contiguous per lane)
//   - P routed through per-wave LDS: b64 writes / b128 reads, conflict-free
// ---------------------------------------------------------------------------

typedef __attribute__((ext_vector_type(8))) short short8_t;   // 8 bf16 (4 VGPR)
typedef __attribute__((ext_vector_type(4))) short short4_t;
typedef __attribute__((ext_vector_type(4))) float f32x4_t;

#define SEQ 2048
#define HEADS 16
#define DK 64
#define DFF 1024

__device__ __forceinline__ unsigned short f32_to_bf16(float f) {
  unsigned int u = __float_as_uint(f);
  u += 0x7FFFu + ((u >> 16) & 1u);   // round-to-nearest-even
  return (unsigned short)(u >> 16);
}
__device__ __forceinline__ float bf16_to_f32(unsigned short h) {
  return __uint_as_float(((unsigned int)h) << 16);
}

__device__ __forceinline__ void gload_lds16(const void* g, void* l) {
  __builtin_amdgcn_global_load_lds(
      (__attribute__((address_space(1))) void*)(g),
      (__attribute__((address_space(3))) void*)(l), 16, 0, 0);
}

// ---------------------------------------------------------------------------
// converters
// ---------------------------------------------------------------------------
__global__ void cvt_f32_bf16_kernel(const float* __restrict__ in,
                                    short* __restrict__ out, int n) {
  int i = (blockIdx.x * 256 + threadIdx.x) * 4;
  if (i >= n) return;
  float4 f = *(const float4*)(in + i);
  short4_t s;
  s[0] = (short)f32_to_bf16(f.x);
  s[1] = (short)f32_to_bf16(f.y);
  s[2] = (short)f32_to_bf16(f.z);
  s[3] = (short)f32_to_bf16(f.w);
  *(short4_t*)(out + i) = s;
}

__global__ void cvt_split_kernel(const float* __restrict__ in,
                                 short* __restrict__ hi,
                                 short* __restrict__ lo, int n) {
  int i = (blockIdx.x * 256 + threadIdx.x) * 4;
  if (i >= n) return;
  float4 f = *(const float4*)(in + i);
  short4_t h, l;
  float ff[4] = {f.x, f.y, f.z, f.w};
#pragma unroll
  for (int j = 0; j < 4; ++j) {
    unsigned short hh = f32_to_bf16(ff[j]);
    h[j] = (short)hh;
    l[j] = (short)f32_to_bf16(ff[j] - bf16_to_f32(hh));
  }
  *(short4_t*)(hi + i) = h;
  *(short4_t*)(lo + i) = l;
}

// ---------------------------------------------------------------------------
// Plain GEMM C[M,N] = A[M,K] @ Bw[N,K]^T (bf16 in, fp32 accum), 128x128/BK=32
// EPI 0: bf16 head-split [B,H,S,64]; EPI 1: fp32 row-major;
// EPI 2: bf16 head-split TRANSPOSED [B,H,64,S]  (for V)
// ---------------------------------------------------------------------------
template <int EPI>
__global__ __launch_bounds__(256, 2) void gemm_bt(
    const short* __restrict__ A, const short* __restrict__ Bw,
    void* __restrict__ Cout, int M, int N, int K) {
  __shared__ short As[128 * 32];
  __shared__ short Bs[128 * 32];

  const int tid = threadIdx.x;
  const int w = tid >> 6, l = tid & 63, g = l >> 4, c = l & 15;
  const int wr = w >> 1, wc = w & 1;
  const int m0 = blockIdx.y * 128, n0 = blockIdx.x * 128;

  f32x4_t acc[4][4] = {};

  for (int k0 = 0; k0 < K; k0 += 32) {
#pragma unroll
    for (int j = 0; j < 2; ++j) {
      int e = (w * 2 + j) * 512 + l * 8;
      int r = e >> 5, cc = e & 31;
      gload_lds16(A + (size_t)(m0 + r) * K + k0 + cc, &As[(w * 2 + j) * 512]);
      gload_lds16(Bw + (size_t)(n0 + r) * K + k0 + cc, &Bs[(w * 2 + j) * 512]);
    }
    __syncthreads();

    short8_t a[4], b[4];
#pragma unroll
    for (int mi = 0; mi < 4; ++mi)
      a[mi] = *(const short8_t*)(&As[(wr * 64 + mi * 16 + c) * 32 + g * 8]);
#pragma unroll
    for (int ni = 0; ni < 4; ++ni)
      b[ni] = *(const short8_t*)(&Bs[(wc * 64 + ni * 16 + c) * 32 + g * 8]);
#pragma unroll
    for (int mi = 0; mi < 4; ++mi)
#pragma unroll
      for (int ni = 0; ni < 4; ++ni)
        acc[mi][ni] = __builtin_amdgcn_mfma_f32_16x16x32_bf16(
            a[mi], b[ni], acc[mi][ni], 0, 0, 0);
    __syncthreads();
  }

  // D layout: col = lane&15, row = (lane>>4)*4 + reg
  if (EPI == 0) {
    short* O = (short*)Cout;
#pragma unroll
    for (int mi = 0; mi < 4; ++mi) {
#pragma unroll
      for (int ni = 0; ni < 4; ++ni) {
        int col = n0 + wc * 64 + ni * 16 + c;
        int hh = col >> 6, dd = col & 63;
#pragma unroll
        for (int j = 0; j < 4; ++j) {
          int row = m0 + wr * 64 + mi * 16 + g * 4 + j;
          int bb = row >> 11, ss = row & 2047;
          O[(((size_t)bb * HEADS + hh) * SEQ + ss) * DK + dd] =
              (short)f32_to_bf16(acc[mi][ni][j]);
        }
      }
    }
  } else if (EPI == 1) {
    float* O = (float*)Cout;
#pragma unroll
    for (int mi = 0; mi < 4; ++mi) {
#pragma unroll
      for (int ni = 0; ni < 4; ++ni) {
        int col = n0 + wc * 64 + ni * 16 + c;
#pragma unroll
        for (int j = 0; j < 4; ++j) {
          int row = m0 + wr * 64 + mi * 16 + g * 4 + j;
          O[(size_t)row * N + col] = acc[mi][ni][j];
        }
      }
    }
  } else {
    short* O = (short*)Cout;   // [B,H,DK,SEQ]
#pragma unroll
    for (int mi = 0; mi < 4; ++mi) {
#pragma unroll
      for (int ni = 0; ni < 4; ++ni) {
        int col = n0 + wc * 64 + ni * 16 + c;
        int hh = col >> 6, dd = col & 63;
        int row0 = m0 + wr * 64 + mi * 16 + g * 4;
        int bb = row0 >> 11, ss0 = row0 & 2047;
        short4_t s4;
#pragma unroll
        for (int j = 0; j < 4; ++j) s4[j] = (short)f32_to_bf16(acc[mi][ni][j]);
        *(short4_t*)(&O[(((size_t)bb * HEADS + hh) * DK + dd) * SEQ + ss0]) = s4;
      }
    }
  }
}

// ---------------------------------------------------------------------------
// Split-B GEMM: C = A @ (Bh+Bl)^T, 2 MFMA chains; out = bf16 hi+lo head-split
// ---------------------------------------------------------------------------
__global__ __launch_bounds__(256, 2) void gemm_bt_split(
    const short* __restrict__ A, const short* __restrict__ Bh,
    const short* __restrict__ Bl, short* __restrict__ Ohi,
    short* __restrict__ Olo, int M, int N, int K) {
  __shared__ short As[128 * 32];
  __shared__ short Bsh[128 * 32];
  __shared__ short Bsl[128 * 32];

  const int tid = threadIdx.x;
  const int w = tid >> 6, l = tid & 63, g = l >> 4, c = l & 15;
  const int wr = w >> 1, wc = w & 1;
  const int m0 = blockIdx.y * 128, n0 = blockIdx.x * 128;

  f32x4_t acc[4][4] = {};

  for (int k0 = 0; k0 < K; k0 += 32) {
#pragma unroll
    for (int j = 0; j < 2; ++j) {
      int e = (w * 2 + j) * 512 + l * 8;
      int r = e >> 5, cc = e & 31;
      gload_lds16(A + (size_t)(m0 + r) * K + k0 + cc, &As[(w * 2 + j) * 512]);
      gload_lds16(Bh + (size_t)(n0 + r) * K + k0 + cc, &Bsh[(w * 2 + j) * 512]);
      gload_lds16(Bl + (size_t)(n0 + r) * K + k0 + cc, &Bsl[(w * 2 + j) * 512]);
    }
    __syncthreads();

    short8_t a[4], bh[4], bl[4];
#pragma unroll
    for (int mi = 0; mi < 4; ++mi)
      a[mi] = *(const short8_t*)(&As[(wr * 64 + mi * 16 + c) * 32 + g * 8]);
#pragma unroll
    for (int ni = 0; ni < 4; ++ni) {
      bh[ni] = *(const short8_t*)(&Bsh[(wc * 64 + ni * 16 + c) * 32 + g * 8]);
      bl[ni] = *(const short8_t*)(&Bsl[(wc * 64 + ni * 16 + c) * 32 + g * 8]);
    }
#pragma unroll
    for (int mi = 0; mi < 4; ++mi)
#pragma unroll
      for (int ni = 0; ni < 4; ++ni) {
        acc[mi][ni] = __builtin_amdgcn_mfma_f32_16x16x32_bf16(
            a[mi], bh[ni], acc[mi][ni], 0, 0, 0);
        acc[mi][ni] = __builtin_amdgcn_mfma_f32_16x16x32_bf16(
            a[mi], bl[ni], acc[mi][ni], 0, 0, 0);
      }
    __syncthreads();
  }

#pragma unroll
  for (int mi = 0; mi < 4; ++mi) {
#pragma unroll
    for (int ni = 0; ni < 4; ++ni) {
      int col = n0 + wc * 64 + ni * 16 + c;
      int hh = col >> 6, dd = col & 63;
#pragma unroll
      for (int j = 0; j < 4; ++j) {
        int row = m0 + wr * 64 + mi * 16 + g * 4 + j;
        int bb = row >> 11, ss = row & 2047;
        size_t idx = (((size_t)bb * HEADS + hh) * SEQ + ss) * DK + dd;
        float x = acc[mi][ni][j];
        unsigned short xh = f32_to_bf16(x);
        Ohi[idx] = (short)xh;
        Olo[idx] = (short)f32_to_bf16(x - bf16_to_f32(xh));
      }
    }
  }
}

// ---------------------------------------------------------------------------
// Flash attention v2 (S^T layout). Grid: (B*H, S/128). Block 256 = 4 waves,
// each wave owns 32 q-rows. NO barriers, NO K/V staging.
//   S^T tile: mfma(A=K rows kv, B=Q rows q) -> D[row=kv][col=q]
//   PV: O^T = mfma(A=V^T rows d, B=P rows q) -> D[row=d][col=q]
// qh*/kh*: [B,H,S,64] hi+lo. vt: [B,H,64,S]. mask fp32 [B,1,S,S]. ctx bf16.
// ---------------------------------------------------------------------------
__global__ __launch_bounds__(256, 2) void attn_kernel(
    const short* __restrict__ qhh, const short* __restrict__ qhl,
    const short* __restrict__ khh, const short* __restrict__ khl,
    const short* __restrict__ vt, const float* __restrict__ mask,
    short* __restrict__ ctx) {
  const int bh = blockIdx.x;
  const int b = bh >> 4;
  const int h = bh & 15;
  const int qt = blockIdx.y;
  const int tid = threadIdx.x;
  const int w = tid >> 6, l = tid & 63, g = l >> 4, c = l & 15;

  __shared__ short Ps[4][32 * 72];    // per-wave P tile [q][kv], stride 72
  short* psw = &Ps[w][0];

  const int qrow0 = qt * 128 + w * 32;
  const short* Qbh = qhh + ((size_t)bh * SEQ + qrow0) * DK;
  const short* Qbl = qhl + ((size_t)bh * SEQ + qrow0) * DK;
  const short* Kbh = khh + (size_t)bh * SEQ * DK;
  const short* Kbl = khl + (size_t)bh * SEQ * DK;
  const short* Vb  = vt  + (size_t)bh * DK * SEQ;           // [64][SEQ]
  const float* M0  = mask + (size_t)b * SEQ * SEQ + (size_t)(qrow0 + c) * SEQ;

  // Q frags (B-operand): lane c holds Q row q=mi*16+c, k = ks*32+g*8
  short8_t qfh[2][2], qfl[2][2];
#pragma unroll
  for (int mi = 0; mi < 2; ++mi)
#pragma unroll
    for (int ks = 0; ks < 2; ++ks) {
      qfh[mi][ks] = *(const short8_t*)(Qbh + (size_t)(mi * 16 + c) * DK + ks * 32 + g * 8);
      qfl[mi][ks] = *(const short8_t*)(Qbl + (size_t)(mi * 16 + c) * DK + ks * 32 + g * 8);
    }

  f32x4_t o[4][2] = {};          // o[di][mi]: O^T rows d=di*16+g*4+j, col q
  float mrun[2] = {-1e30f, -1e30f};
  float lrun[2] = {0.f, 0.f};

  for (int kv0 = 0; kv0 < SEQ; kv0 += 64) {
    // ---- S^T = K Q^T (3-chain hi/lo), K frags direct from global ----
    f32x4_t sa[4][2] = {};       // sa[ni][mi]: rows kv=ni*16+g*4+j, col q
#pragma unroll
    for (int ks = 0; ks < 2; ++ks) {
      short8_t ah[4], al[4];
#pragma unroll
      for (int ni = 0; ni < 4; ++ni) {
        size_t ko = (size_t)(kv0 + ni * 16 + c) * DK + ks * 32 + g * 8;
        ah[ni] = *(const short8_t*)(Kbh + ko);
        al[ni] = *(const short8_t*)(Kbl + ko);
      }
#pragma unroll
      for (int ni = 0; ni < 4; ++ni)
#pragma unroll
        for (int mi = 0; mi < 2; ++mi) {
          sa[ni][mi] = __builtin_amdgcn_mfma_f32_16x16x32_bf16(
              ah[ni], qfh[mi][ks], sa[ni][mi], 0, 0, 0);
          sa[ni][mi] = __builtin_amdgcn_mfma_f32_16x16x32_bf16(
              ah[ni], qfl[mi][ks], sa[ni][mi], 0, 0, 0);
          sa[ni][mi] = __builtin_amdgcn_mfma_f32_16x16x32_bf16(
              al[ni], qfh[mi][ks], sa[ni][mi], 0, 0, 0);
        }
    }

    // ---- + additive mask: kv contiguous per lane -> float4 loads ----
#pragma unroll
    for (int mi = 0; mi < 2; ++mi)
#pragma unroll
      for (int ni = 0; ni < 4; ++ni) {
        float4 mv = *(const float4*)(M0 + (size_t)(mi * 16) * SEQ + kv0 + ni * 16 + g * 4);
        sa[ni][mi][0] += mv.x;
        sa[ni][mi][1] += mv.y;
        sa[ni][mi][2] += mv.z;
        sa[ni][mi][3] += mv.w;
      }

    // ---- online softmax: one (m,l) per q-col (per mi) ----
#pragma unroll
    for (int mi = 0; mi < 2; ++mi) {
      float t = sa[0][mi][0];
#pragma unroll
      for (int ni = 0; ni < 4; ++ni)
#pragma unroll
        for (int j = 0; j < 4; ++j) t = fmaxf(t, sa[ni][mi][j]);
      t = fmaxf(t, __shfl_xor(t, 16));
      t = fmaxf(t, __shfl_xor(t, 32));
      float mold = mrun[mi];
      float mnew = fmaxf(mold, t);
      float sc = __expf(mold - mnew);
      mrun[mi] = mnew;
#pragma unroll
      for (int di = 0; di < 4; ++di)
#pragma unroll
        for (int j = 0; j < 4; ++j) o[di][mi][j] *= sc;
      float psum = 0.f;
#pragma unroll
      for (int ni = 0; ni < 4; ++ni) {
        short4_t ph;
#pragma unroll
        for (int j = 0; j < 4; ++j) {
          float p = __expf(sa[ni][mi][j] - mnew);
          psum += p;
          ph[j] = (short)f32_to_bf16(p);
        }
        // P store: [q][kv] A-layout, b64, conflict-free (bank = (4c+2g+8ni)%32)
        *(short4_t*)(&psw[(mi * 16 + c) * 72 + ni * 16 + g * 4]) = ph;
      }
      lrun[mi] = lrun[mi] * sc + psum;
    }

    // ---- O^T += V^T P^T : V frags direct from global ----
#pragma unroll
    for (int ks = 0; ks < 2; ++ks) {
      short8_t pb[2];
#pragma unroll
      for (int mi = 0; mi < 2; ++mi)
        pb[mi] = *(const short8_t*)(&psw[(mi * 16 + c) * 72 + ks * 32 + g * 8]);
#pragma unroll
      for (int di = 0; di < 4; ++di) {
        short8_t av = *(const short8_t*)(Vb + (size_t)(di * 16 + c) * SEQ + kv0 + ks * 32 + g * 8);
#pragma unroll
        for (int mi = 0; mi < 2; ++mi)
          o[di][mi] = __builtin_amdgcn_mfma_f32_16x16x32_bf16(
              av, pb[mi], o[di][mi], 0, 0, 0);
      }
    }
  }

  // ---- finalize: reduce l across g-groups, normalize, short4 stores ----
  float inv[2];
#pragma unroll
  for (int mi = 0; mi < 2; ++mi) {
    float s = lrun[mi];
    s += __shfl_xor(s, 16);
    s += __shfl_xor(s, 32);
    inv[mi] = 1.f / s;
  }
  short* Cb = ctx + ((size_t)b * SEQ + qrow0) * DFF + h * DK;
#pragma unroll
  for (int mi = 0; mi < 2; ++mi)
#pragma unroll
    for (int di = 0; di < 4; ++di) {
      short4_t s4;
#pragma unroll
      for (int j = 0; j < 4; ++j)
        s4[j] = (short)f32_to_bf16(o[di][mi][j] * inv[mi]);
      *(short4_t*)(Cb + (size_t)(mi * 16 + c) * DFF + di * 16 + g * 4) = s4;
    }
}

// ---------------------------------------------------------------------------
extern "C" void kernel_launch(void* const* d_in, const int* in_sizes, int n_in,
                              void* d_out, int out_size, void* d_ws, size_t ws_size,
                              hipStream_t stream) {
  const float* q    = (const float*)d_in[0];
  const float* k    = (const float*)d_in[1];
  const float* v    = (const float*)d_in[2];
  const float* mask = (const float*)d_in[3];
  const float* Wq   = (const float*)d_in[4];
  const float* Wk   = (const float*)d_in[5];
  const float* Wv   = (const float*)d_in[6];
  const float* Wo   = (const float*)d_in[7];
  float* out = (float*)d_out;

  const size_t NQ = 4194304;   // 4096*1024
  const size_t NW = 1048576;   // 1024*1024
  short* ws   = (short*)d_ws;
  short* qbf  = ws;            // A0; reused as kh_h after proj Q
  short* kbf  = ws + NQ;       // A1; reused as vt after proj K
  short* vbf  = ws + 2 * NQ;   // A2; reused as ctx after proj V
  short* qh_h = ws + 3 * NQ;
  short* qh_l = ws + 4 * NQ;
  short* kh_l = ws + 5 * NQ;
  short* wq_h = ws + 6 * NQ;
  short* wq_l = wq_h + NW;
  short* wk_h = wq_l + NW;
  short* wk_l = wk_h + NW;
  short* wvb  = wk_l + NW;
  short* wob  = wvb + NW;      // total 6*NQ + 6*NW shorts = 62.9 MB

  short* kh_h = qbf;   // aliases (stream-ordered, safe)
  short* vtp  = kbf;   // V transposed [B,H,64,S]
  short* ctx  = vbf;

  cvt_f32_bf16_kernel<<<4096, 256, 0, stream>>>(q, qbf, (int)NQ);
  cvt_f32_bf16_kernel<<<4096, 256, 0, stream>>>(k, kbf, (int)NQ);
  cvt_f32_bf16_kernel<<<4096, 256, 0, stream>>>(v, vbf, (int)NQ);
  cvt_split_kernel<<<1024, 256, 0, stream>>>(Wq, wq_h, wq_l, (int)NW);
  cvt_split_kernel<<<1024, 256, 0, stream>>>(Wk, wk_h, wk_l, (int)NW);
  cvt_f32_bf16_kernel<<<1024, 256, 0, stream>>>(Wv, wvb, (int)NW);
  cvt_f32_bf16_kernel<<<1024, 256, 0, stream>>>(Wo, wob, (int)NW);

  dim3 gg(8, 32);   // N/128, M/128
  gemm_bt_split<<<gg, 256, 0, stream>>>(qbf, wq_h, wq_l, qh_h, qh_l, 4096, 1024, 1024);
  gemm_bt_split<<<gg, 256, 0, stream>>>(kbf, wk_h, wk_l, kh_h, kh_l, 4096, 1024, 1024);
  gemm_bt<2><<<gg, 256, 0, stream>>>(vbf, wvb, vtp, 4096, 1024, 1024);

  attn_kernel<<<dim3(32, 16), 256, 0, stream>>>(qh_h, qh_l, kh_h, kh_l, vtp, mask, ctx);

  gemm_bt<1><<<gg, 256, 0, stream>>>(ctx, wob, out, 4096, 1024, 1024);
}

// Round 5
// 258.054 us; speedup vs baseline: 1.4933x; 1.4933x over previous
//
#include <hip/hip_runtime.h>
#include <hip/hip_bf16.h>

// ---------------------------------------------------------------------------
// T5 MHA: B=2, S=2048, D_FF=1024, H=16, DK=64, INNER=1024
// QK^T path at ~fp24 via bf16 hi+lo splits (3-chain MFMA). V path plain bf16.
// Attn v3b: S^T swapped layout + cooperative LDS staging + issue-early
// prefetch. FIX vs v3: each thread stages 16 shorts/buffer (full coverage).
// ---------------------------------------------------------------------------

typedef __attribute__((ext_vector_type(8))) short short8_t;   // 8 bf16 (4 VGPR)
typedef __attribute__((ext_vector_type(4))) short short4_t;
typedef __attribute__((ext_vector_type(4))) float f32x4_t;

#define SEQ 2048
#define HEADS 16
#define DK 64
#define DFF 1024

__device__ __forceinline__ unsigned short f32_to_bf16(float f) {
  unsigned int u = __float_as_uint(f);
  u += 0x7FFFu + ((u >> 16) & 1u);   // round-to-nearest-even
  return (unsigned short)(u >> 16);
}
__device__ __forceinline__ float bf16_to_f32(unsigned short h) {
  return __uint_as_float(((unsigned int)h) << 16);
}

__device__ __forceinline__ void gload_lds16(const void* g, void* l) {
  __builtin_amdgcn_global_load_lds(
      (__attribute__((address_space(1))) void*)(g),
      (__attribute__((address_space(3))) void*)(l), 16, 0, 0);
}

// ---------------------------------------------------------------------------
// converters
// ---------------------------------------------------------------------------
__global__ void cvt_f32_bf16_kernel(const float* __restrict__ in,
                                    short* __restrict__ out, int n) {
  int i = (blockIdx.x * 256 + threadIdx.x) * 4;
  if (i >= n) return;
  float4 f = *(const float4*)(in + i);
  short4_t s;
  s[0] = (short)f32_to_bf16(f.x);
  s[1] = (short)f32_to_bf16(f.y);
  s[2] = (short)f32_to_bf16(f.z);
  s[3] = (short)f32_to_bf16(f.w);
  *(short4_t*)(out + i) = s;
}

__global__ void cvt_split_kernel(const float* __restrict__ in,
                                 short* __restrict__ hi,
                                 short* __restrict__ lo, int n) {
  int i = (blockIdx.x * 256 + threadIdx.x) * 4;
  if (i >= n) return;
  float4 f = *(const float4*)(in + i);
  short4_t h, l;
  float ff[4] = {f.x, f.y, f.z, f.w};
#pragma unroll
  for (int j = 0; j < 4; ++j) {
    unsigned short hh = f32_to_bf16(ff[j]);
    h[j] = (short)hh;
    l[j] = (short)f32_to_bf16(ff[j] - bf16_to_f32(hh));
  }
  *(short4_t*)(hi + i) = h;
  *(short4_t*)(lo + i) = l;
}

// ---------------------------------------------------------------------------
// Plain GEMM C[M,N] = A[M,K] @ Bw[N,K]^T (bf16 in, fp32 accum), 128x128/BK=32
// EPI 0: bf16 head-split [B,H,S,64]; EPI 1: fp32 row-major;
// EPI 2: bf16 head-split TRANSPOSED [B,H,64,S]  (for V)
// ---------------------------------------------------------------------------
template <int EPI>
__global__ __launch_bounds__(256, 2) void gemm_bt(
    const short* __restrict__ A, const short* __restrict__ Bw,
    void* __restrict__ Cout, int M, int N, int K) {
  __shared__ short As[128 * 32];
  __shared__ short Bs[128 * 32];

  const int tid = threadIdx.x;
  const int w = tid >> 6, l = tid & 63, g = l >> 4, c = l & 15;
  const int wr = w >> 1, wc = w & 1;
  const int m0 = blockIdx.y * 128, n0 = blockIdx.x * 128;

  f32x4_t acc[4][4] = {};

  for (int k0 = 0; k0 < K; k0 += 32) {
#pragma unroll
    for (int j = 0; j < 2; ++j) {
      int e = (w * 2 + j) * 512 + l * 8;
      int r = e >> 5, cc = e & 31;
      gload_lds16(A + (size_t)(m0 + r) * K + k0 + cc, &As[(w * 2 + j) * 512]);
      gload_lds16(Bw + (size_t)(n0 + r) * K + k0 + cc, &Bs[(w * 2 + j) * 512]);
    }
    __syncthreads();

    short8_t a[4], b[4];
#pragma unroll
    for (int mi = 0; mi < 4; ++mi)
      a[mi] = *(const short8_t*)(&As[(wr * 64 + mi * 16 + c) * 32 + g * 8]);
#pragma unroll
    for (int ni = 0; ni < 4; ++ni)
      b[ni] = *(const short8_t*)(&Bs[(wc * 64 + ni * 16 + c) * 32 + g * 8]);
#pragma unroll
    for (int mi = 0; mi < 4; ++mi)
#pragma unroll
      for (int ni = 0; ni < 4; ++ni)
        acc[mi][ni] = __builtin_amdgcn_mfma_f32_16x16x32_bf16(
            a[mi], b[ni], acc[mi][ni], 0, 0, 0);
    __syncthreads();
  }

  // D layout: col = lane&15, row = (lane>>4)*4 + reg
  if (EPI == 0) {
    short* O = (short*)Cout;
#pragma unroll
    for (int mi = 0; mi < 4; ++mi) {
#pragma unroll
      for (int ni = 0; ni < 4; ++ni) {
        int col = n0 + wc * 64 + ni * 16 + c;
        int hh = col >> 6, dd = col & 63;
#pragma unroll
        for (int j = 0; j < 4; ++j) {
          int row = m0 + wr * 64 + mi * 16 + g * 4 + j;
          int bb = row >> 11, ss = row & 2047;
          O[(((size_t)bb * HEADS + hh) * SEQ + ss) * DK + dd] =
              (short)f32_to_bf16(acc[mi][ni][j]);
        }
      }
    }
  } else if (EPI == 1) {
    float* O = (float*)Cout;
#pragma unroll
    for (int mi = 0; mi < 4; ++mi) {
#pragma unroll
      for (int ni = 0; ni < 4; ++ni) {
        int col = n0 + wc * 64 + ni * 16 + c;
#pragma unroll
        for (int j = 0; j < 4; ++j) {
          int row = m0 + wr * 64 + mi * 16 + g * 4 + j;
          O[(size_t)row * N + col] = acc[mi][ni][j];
        }
      }
    }
  } else {
    short* O = (short*)Cout;   // [B,H,DK,SEQ]
#pragma unroll
    for (int mi = 0; mi < 4; ++mi) {
#pragma unroll
      for (int ni = 0; ni < 4; ++ni) {
        int col = n0 + wc * 64 + ni * 16 + c;
        int hh = col >> 6, dd = col & 63;
        int row0 = m0 + wr * 64 + mi * 16 + g * 4;
        int bb = row0 >> 11, ss0 = row0 & 2047;
        short4_t s4;
#pragma unroll
        for (int j = 0; j < 4; ++j) s4[j] = (short)f32_to_bf16(acc[mi][ni][j]);
        *(short4_t*)(&O[(((size_t)bb * HEADS + hh) * DK + dd) * SEQ + ss0]) = s4;
      }
    }
  }
}

// ---------------------------------------------------------------------------
// Split-B GEMM: C = A @ (Bh+Bl)^T, 2 MFMA chains; out = bf16 hi+lo head-split
// ---------------------------------------------------------------------------
__global__ __launch_bounds__(256, 2) void gemm_bt_split(
    const short* __restrict__ A, const short* __restrict__ Bh,
    const short* __restrict__ Bl, short* __restrict__ Ohi,
    short* __restrict__ Olo, int M, int N, int K) {
  __shared__ short As[128 * 32];
  __shared__ short Bsh[128 * 32];
  __shared__ short Bsl[128 * 32];

  const int tid = threadIdx.x;
  const int w = tid >> 6, l = tid & 63, g = l >> 4, c = l & 15;
  const int wr = w >> 1, wc = w & 1;
  const int m0 = blockIdx.y * 128, n0 = blockIdx.x * 128;

  f32x4_t acc[4][4] = {};

  for (int k0 = 0; k0 < K; k0 += 32) {
#pragma unroll
    for (int j = 0; j < 2; ++j) {
      int e = (w * 2 + j) * 512 + l * 8;
      int r = e >> 5, cc = e & 31;
      gload_lds16(A + (size_t)(m0 + r) * K + k0 + cc, &As[(w * 2 + j) * 512]);
      gload_lds16(Bh + (size_t)(n0 + r) * K + k0 + cc, &Bsh[(w * 2 + j) * 512]);
      gload_lds16(Bl + (size_t)(n0 + r) * K + k0 + cc, &Bsl[(w * 2 + j) * 512]);
    }
    __syncthreads();

    short8_t a[4], bh[4], bl[4];
#pragma unroll
    for (int mi = 0; mi < 4; ++mi)
      a[mi] = *(const short8_t*)(&As[(wr * 64 + mi * 16 + c) * 32 + g * 8]);
#pragma unroll
    for (int ni = 0; ni < 4; ++ni) {
      bh[ni] = *(const short8_t*)(&Bsh[(wc * 64 + ni * 16 + c) * 32 + g * 8]);
      bl[ni] = *(const short8_t*)(&Bsl[(wc * 64 + ni * 16 + c) * 32 + g * 8]);
    }
#pragma unroll
    for (int mi = 0; mi < 4; ++mi)
#pragma unroll
      for (int ni = 0; ni < 4; ++ni) {
        acc[mi][ni] = __builtin_amdgcn_mfma_f32_16x16x32_bf16(
            a[mi], bh[ni], acc[mi][ni], 0, 0, 0);
        acc[mi][ni] = __builtin_amdgcn_mfma_f32_16x16x32_bf16(
            a[mi], bl[ni], acc[mi][ni], 0, 0, 0);
      }
    __syncthreads();
  }

#pragma unroll
  for (int mi = 0; mi < 4; ++mi) {
#pragma unroll
    for (int ni = 0; ni < 4; ++ni) {
      int col = n0 + wc * 64 + ni * 16 + c;
      int hh = col >> 6, dd = col & 63;
#pragma unroll
      for (int j = 0; j < 4; ++j) {
        int row = m0 + wr * 64 + mi * 16 + g * 4 + j;
        int bb = row >> 11, ss = row & 2047;
        size_t idx = (((size_t)bb * HEADS + hh) * SEQ + ss) * DK + dd;
        float x = acc[mi][ni][j];
        unsigned short xh = f32_to_bf16(x);
        Ohi[idx] = (short)xh;
        Olo[idx] = (short)f32_to_bf16(x - bf16_to_f32(xh));
      }
    }
  }
}

// ---------------------------------------------------------------------------
// Flash attention v3b. Grid: (B*H, S/128). Block 256 = 4 waves x 32 q-rows.
// S^T tile: mfma(A=K rows kv, B=Q rows q) -> D[row=kv][col=q]
// PV: O^T = mfma(A=V^T rows d, B=P rows q) -> D[row=d][col=q]
// K hi/lo + V^T staged in LDS (stride-72 pad); each thread stages 16 shorts
// per buffer (srow=tid>>2, cols [scol,scol+16)) -> full 64x64 coverage.
// Issue-early prefetch of next chunk overlaps compute.
// ---------------------------------------------------------------------------
__global__ __launch_bounds__(256, 2) void attn_kernel(
    const short* __restrict__ qhh, const short* __restrict__ qhl,
    const short* __restrict__ khh, const short* __restrict__ khl,
    const short* __restrict__ vt, const float* __restrict__ mask,
    short* __restrict__ ctx) {
  const int bh = blockIdx.x;
  const int b = bh >> 4;
  const int h = bh & 15;
  const int qt = blockIdx.y;
  const int tid = threadIdx.x;
  const int w = tid >> 6, l = tid & 63, g = l >> 4, c = l & 15;

  __shared__ short Khs[64 * 72];      // K chunk hi [kv][k], stride 72
  __shared__ short Kls[64 * 72];      // K chunk lo
  __shared__ short Vts[64 * 72];      // V^T chunk [d][kv], stride 72
  __shared__ short Ps[4][32 * 72];    // per-wave P tile [q][kv]
  short* psw = &Ps[w][0];

  const int qrow0 = qt * 128 + w * 32;
  const short* Qbh = qhh + ((size_t)bh * SEQ + qrow0) * DK;
  const short* Qbl = qhl + ((size_t)bh * SEQ + qrow0) * DK;
  const short* Kbh = khh + (size_t)bh * SEQ * DK;
  const short* Kbl = khl + (size_t)bh * SEQ * DK;
  const short* Vb  = vt  + (size_t)bh * DK * SEQ;           // [64][SEQ]
  const float* M0  = mask + (size_t)b * SEQ * SEQ + (size_t)(qrow0 + c) * SEQ;

  // staging: each thread copies 16 contiguous shorts per buffer
  const int srow = tid >> 2;            // 0..63
  const int scol = (tid & 3) * 16;      // 0,16,32,48
  const int sofs = srow * 72 + scol;

  // Q frags (B-operand): lane c holds Q row q=mi*16+c, k = ks*32+g*8
  short8_t qfh[2][2], qfl[2][2];
#pragma unroll
  for (int mi = 0; mi < 2; ++mi)
#pragma unroll
    for (int ks = 0; ks < 2; ++ks) {
      qfh[mi][ks] = *(const short8_t*)(Qbh + (size_t)(mi * 16 + c) * DK + ks * 32 + g * 8);
      qfl[mi][ks] = *(const short8_t*)(Qbl + (size_t)(mi * 16 + c) * DK + ks * 32 + g * 8);
    }

  // prologue: load chunk 0 into staging regs (2x short8 per buffer)
  short8_t rkh0 = *(const short8_t*)(Kbh + (size_t)srow * DK + scol);
  short8_t rkh1 = *(const short8_t*)(Kbh + (size_t)srow * DK + scol + 8);
  short8_t rkl0 = *(const short8_t*)(Kbl + (size_t)srow * DK + scol);
  short8_t rkl1 = *(const short8_t*)(Kbl + (size_t)srow * DK + scol + 8);
  short8_t rv0  = *(const short8_t*)(Vb  + (size_t)srow * SEQ + scol);
  short8_t rv1  = *(const short8_t*)(Vb  + (size_t)srow * SEQ + scol + 8);

  f32x4_t o[4][2] = {};          // o[di][mi]: O^T rows d=di*16+g*4+j, col q
  float mrun[2] = {-1e30f, -1e30f};
  float lrun[2] = {0.f, 0.f};

  for (int kv0 = 0; kv0 < SEQ; kv0 += 64) {
    __syncthreads();             // prev iter's readers done (also drains loads)
    *(short8_t*)(&Khs[sofs]) = rkh0;
    *(short8_t*)(&Khs[sofs + 8]) = rkh1;
    *(short8_t*)(&Kls[sofs]) = rkl0;
    *(short8_t*)(&Kls[sofs + 8]) = rkl1;
    *(short8_t*)(&Vts[sofs]) = rv0;
    *(short8_t*)(&Vts[sofs + 8]) = rv1;
    __syncthreads();             // staged data visible to all waves

    // issue-early: next chunk's loads overlap this iteration's compute
    if (kv0 + 64 < SEQ) {
      int kv1 = kv0 + 64;
      rkh0 = *(const short8_t*)(Kbh + (size_t)(kv1 + srow) * DK + scol);
      rkh1 = *(const short8_t*)(Kbh + (size_t)(kv1 + srow) * DK + scol + 8);
      rkl0 = *(const short8_t*)(Kbl + (size_t)(kv1 + srow) * DK + scol);
      rkl1 = *(const short8_t*)(Kbl + (size_t)(kv1 + srow) * DK + scol + 8);
      rv0  = *(const short8_t*)(Vb  + (size_t)srow * SEQ + kv1 + scol);
      rv1  = *(const short8_t*)(Vb  + (size_t)srow * SEQ + kv1 + scol + 8);
    }

    // ---- S^T = K Q^T (3-chain hi/lo), K frags from LDS ----
    f32x4_t sa[4][2] = {};       // sa[ni][mi]: rows kv=ni*16+g*4+j, col q
#pragma unroll
    for (int ks = 0; ks < 2; ++ks) {
      short8_t ah[4], al[4];
#pragma unroll
      for (int ni = 0; ni < 4; ++ni) {
        ah[ni] = *(const short8_t*)(&Khs[(ni * 16 + c) * 72 + ks * 32 + g * 8]);
        al[ni] = *(const short8_t*)(&Kls[(ni * 16 + c) * 72 + ks * 32 + g * 8]);
      }
#pragma unroll
      for (int ni = 0; ni < 4; ++ni)
#pragma unroll
        for (int mi = 0; mi < 2; ++mi) {
          sa[ni][mi] = __builtin_amdgcn_mfma_f32_16x16x32_bf16(
              ah[ni], qfh[mi][ks], sa[ni][mi], 0, 0, 0);
          sa[ni][mi] = __builtin_amdgcn_mfma_f32_16x16x32_bf16(
              ah[ni], qfl[mi][ks], sa[ni][mi], 0, 0, 0);
          sa[ni][mi] = __builtin_amdgcn_mfma_f32_16x16x32_bf16(
              al[ni], qfh[mi][ks], sa[ni][mi], 0, 0, 0);
        }
    }

    // ---- + additive mask: kv contiguous per lane -> float4 loads ----
#pragma unroll
    for (int mi = 0; mi < 2; ++mi)
#pragma unroll
      for (int ni = 0; ni < 4; ++ni) {
        float4 mv = *(const float4*)(M0 + (size_t)(mi * 16) * SEQ + kv0 + ni * 16 + g * 4);
        sa[ni][mi][0] += mv.x;
        sa[ni][mi][1] += mv.y;
        sa[ni][mi][2] += mv.z;
        sa[ni][mi][3] += mv.w;
      }

    // ---- online softmax: one (m,l) per q-col (per mi) ----
#pragma unroll
    for (int mi = 0; mi < 2; ++mi) {
      float t = sa[0][mi][0];
#pragma unroll
      for (int ni = 0; ni < 4; ++ni)
#pragma unroll
        for (int j = 0; j < 4; ++j) t = fmaxf(t, sa[ni][mi][j]);
      t = fmaxf(t, __shfl_xor(t, 16));
      t = fmaxf(t, __shfl_xor(t, 32));
      float mold = mrun[mi];
      float mnew = fmaxf(mold, t);
      float sc = __expf(mold - mnew);
      mrun[mi] = mnew;
#pragma unroll
      for (int di = 0; di < 4; ++di)
#pragma unroll
        for (int j = 0; j < 4; ++j) o[di][mi][j] *= sc;
      float psum = 0.f;
#pragma unroll
      for (int ni = 0; ni < 4; ++ni) {
        short4_t ph;
#pragma unroll
        for (int j = 0; j < 4; ++j) {
          float p = __expf(sa[ni][mi][j] - mnew);
          psum += p;
          ph[j] = (short)f32_to_bf16(p);
        }
        // P store: [q][kv] A-layout, b64, conflict-free
        *(short4_t*)(&psw[(mi * 16 + c) * 72 + ni * 16 + g * 4]) = ph;
      }
      lrun[mi] = lrun[mi] * sc + psum;
    }

    // ---- O^T += V^T P^T : V frags from LDS ----
#pragma unroll
    for (int ks = 0; ks < 2; ++ks) {
      short8_t pb[2];
#pragma unroll
      for (int mi = 0; mi < 2; ++mi)
        pb[mi] = *(const short8_t*)(&psw[(mi * 16 + c) * 72 + ks * 32 + g * 8]);
#pragma unroll
      for (int di = 0; di < 4; ++di) {
        short8_t av = *(const short8_t*)(&Vts[(di * 16 + c) * 72 + ks * 32 + g * 8]);
#pragma unroll
        for (int mi = 0; mi < 2; ++mi)
          o[di][mi] = __builtin_amdgcn_mfma_f32_16x16x32_bf16(
              av, pb[mi], o[di][mi], 0, 0, 0);
      }
    }
  }

  // ---- finalize: reduce l across g-groups, normalize, short4 stores ----
  float inv[2];
#pragma unroll
  for (int mi = 0; mi < 2; ++mi) {
    float s = lrun[mi];
    s += __shfl_xor(s, 16);
    s += __shfl_xor(s, 32);
    inv[mi] = 1.f / s;
  }
  short* Cb = ctx + ((size_t)b * SEQ + qrow0) * DFF + h * DK;
#pragma unroll
  for (int mi = 0; mi < 2; ++mi)
#pragma unroll
    for (int di = 0; di < 4; ++di) {
      short4_t s4;
#pragma unroll
      for (int j = 0; j < 4; ++j)
        s4[j] = (short)f32_to_bf16(o[di][mi][j] * inv[mi]);
      *(short4_t*)(Cb + (size_t)(mi * 16 + c) * DFF + di * 16 + g * 4) = s4;
    }
}

// ---------------------------------------------------------------------------
extern "C" void kernel_launch(void* const* d_in, const int* in_sizes, int n_in,
                              void* d_out, int out_size, void* d_ws, size_t ws_size,
                              hipStream_t stream) {
  const float* q    = (const float*)d_in[0];
  const float* k    = (const float*)d_in[1];
  const float* v    = (const float*)d_in[2];
  const float* mask = (const float*)d_in[3];
  const float* Wq   = (const float*)d_in[4];
  const float* Wk   = (const float*)d_in[5];
  const float* Wv   = (const float*)d_in[6];
  const float* Wo   = (const float*)d_in[7];
  float* out = (float*)d_out;

  const size_t NQ = 4194304;   // 4096*1024
  const size_t NW = 1048576;   // 1024*1024
  short* ws   = (short*)d_ws;
  short* qbf  = ws;            // A0; reused as kh_h after proj Q
  short* kbf  = ws + NQ;       // A1; reused as vt after proj K
  short* vbf  = ws + 2 * NQ;   // A2; reused as ctx after proj V
  short* qh_h = ws + 3 * NQ;
  short* qh_l = ws + 4 * NQ;
  short* kh_l = ws + 5 * NQ;
  short* wq_h = ws + 6 * NQ;
  short* wq_l = wq_h + NW;
  short* wk_h = wq_l + NW;
  short* wk_l = wk_h + NW;
  short* wvb  = wk_l + NW;
  short* wob  = wvb + NW;      // total 6*NQ + 6*NW shorts = 62.9 MB

  short* kh_h = qbf;   // aliases (stream-ordered, safe)
  short* vtp  = kbf;   // V transposed [B,H,64,S]
  short* ctx  = vbf;

  cvt_f32_bf16_kernel<<<4096, 256, 0, stream>>>(q, qbf, (int)NQ);
  cvt_f32_bf16_kernel<<<4096, 256, 0, stream>>>(k, kbf, (int)NQ);
  cvt_f32_bf16_kernel<<<4096, 256, 0, stream>>>(v, vbf, (int)NQ);
  cvt_split_kernel<<<1024, 256, 0, stream>>>(Wq, wq_h, wq_l, (int)NW);
  cvt_split_kernel<<<1024, 256, 0, stream>>>(Wk, wk_h, wk_l, (int)NW);
  cvt_f32_bf16_kernel<<<1024, 256, 0, stream>>>(Wv, wvb, (int)NW);
  cvt_f32_bf16_kernel<<<1024, 256, 0, stream>>>(Wo, wob, (int)NW);

  dim3 gg(8, 32);   // N/128, M/128
  gemm_bt_split<<<gg, 256, 0, stream>>>(qbf, wq_h, wq_l, qh_h, qh_l, 4096, 1024, 1024);
  gemm_bt_split<<<gg, 256, 0, stream>>>(kbf, wk_h, wk_l, kh_h, kh_l, 4096, 1024, 1024);
  gemm_bt<2><<<gg, 256, 0, stream>>>(vbf, wvb, vtp, 4096, 1024, 1024);

  attn_kernel<<<dim3(32, 16), 256, 0, stream>>>(qh_h, qh_l, kh_h, kh_l, vtp, mask, ctx);

  gemm_bt<1><<<gg, 256, 0, stream>>>(ctx, wob, out, 4096, 1024, 1024);
}

// Round 6
// 211.267 us; speedup vs baseline: 1.8240x; 1.2215x over previous
//
#include <hip/hip_runtime.h>
#include <hip/hip_bf16.h>

// ---------------------------------------------------------------------------
// T5 MHA: B=2, S=2048, D_FF=1024, H=16, DK=64, INNER=1024
// Precision: q carried hi+lo (2-chain QK vs k_hi); W's split for projections.
// Attn v4: S^T layout, K-hi + V^T LDS staging, issue-early K/V prefetch,
//          mask register prefetch. GEMMs: 128x64 tiles (2 blocks/CU).
// ---------------------------------------------------------------------------

typedef __attribute__((ext_vector_type(8))) short short8_t;   // 8 bf16 (4 VGPR)
typedef __attribute__((ext_vector_type(4))) short short4_t;
typedef __attribute__((ext_vector_type(4))) float f32x4_t;

#define SEQ 2048
#define HEADS 16
#define DK 64
#define DFF 1024

__device__ __forceinline__ unsigned short f32_to_bf16(float f) {
  unsigned int u = __float_as_uint(f);
  u += 0x7FFFu + ((u >> 16) & 1u);   // round-to-nearest-even
  return (unsigned short)(u >> 16);
}
__device__ __forceinline__ float bf16_to_f32(unsigned short h) {
  return __uint_as_float(((unsigned int)h) << 16);
}

__device__ __forceinline__ void gload_lds16(const void* g, void* l) {
  __builtin_amdgcn_global_load_lds(
      (__attribute__((address_space(1))) void*)(g),
      (__attribute__((address_space(3))) void*)(l), 16, 0, 0);
}

// ---------------------------------------------------------------------------
// cvt_x: q/k/v fp32 -> bf16, one dispatch (blockIdx.y selects tensor)
// ---------------------------------------------------------------------------
__global__ void cvt_x_kernel(const float* __restrict__ q,
                             const float* __restrict__ k,
                             const float* __restrict__ v,
                             short* __restrict__ dst, int n) {
  const float* src = (blockIdx.y == 0) ? q : (blockIdx.y == 1) ? k : v;
  short* out = dst + (size_t)blockIdx.y * n;
  int i = (blockIdx.x * 256 + threadIdx.x) * 4;
  if (i >= n) return;
  float4 f = *(const float4*)(src + i);
  short4_t s;
  s[0] = (short)f32_to_bf16(f.x);
  s[1] = (short)f32_to_bf16(f.y);
  s[2] = (short)f32_to_bf16(f.z);
  s[3] = (short)f32_to_bf16(f.w);
  *(short4_t*)(out + i) = s;
}

// ---------------------------------------------------------------------------
// cvt_w: y<3 -> split W[y] into hi+lo pair; y==3 -> plain Wo
// W region layout: [wq_h, wq_l, wk_h, wk_l, wv_h, wv_l, wob], NW each
// ---------------------------------------------------------------------------
__global__ void cvt_w_kernel(const float* __restrict__ Wq,
                             const float* __restrict__ Wk,
                             const float* __restrict__ Wv,
                             const float* __restrict__ Wo,
                             short* __restrict__ wbase, int n) {
  int y = blockIdx.y;
  const float* src = (y == 0) ? Wq : (y == 1) ? Wk : (y == 2) ? Wv : Wo;
  int i = (blockIdx.x * 256 + threadIdx.x) * 4;
  if (i >= n) return;
  float4 f = *(const float4*)(src + i);
  float ff[4] = {f.x, f.y, f.z, f.w};
  if (y < 3) {
    short* hi = wbase + (size_t)(2 * y) * n;
    short* lo = wbase + (size_t)(2 * y + 1) * n;
    short4_t h, l;
#pragma unroll
    for (int j = 0; j < 4; ++j) {
      unsigned short hh = f32_to_bf16(ff[j]);
      h[j] = (short)hh;
      l[j] = (short)f32_to_bf16(ff[j] - bf16_to_f32(hh));
    }
    *(short4_t*)(hi + i) = h;
    *(short4_t*)(lo + i) = l;
  } else {
    short* out = wbase + (size_t)6 * n;
    short4_t s;
#pragma unroll
    for (int j = 0; j < 4; ++j) s[j] = (short)f32_to_bf16(ff[j]);
    *(short4_t*)(out + i) = s;
  }
}

// ---------------------------------------------------------------------------
// Projection GEMM: C[M,1024] = A[M,K] @ (Bh+Bl)[1024,K]^T, 2 MFMA chains.
// Tile 128M x 64N, BK=32, 256 thr (4 waves 2x2; per wave 64x32 = 4x2 frags).
// EPI 0: bf16 hi+lo head-split [B,H,S,64] (Q)
// EPI 1: bf16 hi head-split (K)
// EPI 2: bf16 hi TRANSPOSED [B,H,64,S] (V)
// ---------------------------------------------------------------------------
template <int EPI>
__global__ __launch_bounds__(256, 2) void gemm_proj(
    const short* __restrict__ A, const short* __restrict__ Bh,
    const short* __restrict__ Bl, short* __restrict__ Ohi,
    short* __restrict__ Olo, int M, int K) {
  __shared__ short As[128 * 32];
  __shared__ short Bsh[64 * 32];
  __shared__ short Bsl[64 * 32];

  const int tid = threadIdx.x;
  const int w = tid >> 6, l = tid & 63, g = l >> 4, c = l & 15;
  const int wr = w >> 1, wc = w & 1;
  const int m0 = blockIdx.y * 128, n0 = blockIdx.x * 64;

  f32x4_t acc[4][2] = {};

  for (int k0 = 0; k0 < K; k0 += 32) {
#pragma unroll
    for (int j = 0; j < 2; ++j) {
      int e = (w * 2 + j) * 512 + l * 8;
      int r = e >> 5, cc = e & 31;
      gload_lds16(A + (size_t)(m0 + r) * K + k0 + cc, &As[(w * 2 + j) * 512]);
    }
    {
      int e = w * 512 + l * 8;
      int r = e >> 5, cc = e & 31;
      gload_lds16(Bh + (size_t)(n0 + r) * K + k0 + cc, &Bsh[w * 512]);
      gload_lds16(Bl + (size_t)(n0 + r) * K + k0 + cc, &Bsl[w * 512]);
    }
    __syncthreads();

    short8_t a[4], bh[2], bl[2];
#pragma unroll
    for (int mi = 0; mi < 4; ++mi)
      a[mi] = *(const short8_t*)(&As[(wr * 64 + mi * 16 + c) * 32 + g * 8]);
#pragma unroll
    for (int ni = 0; ni < 2; ++ni) {
      bh[ni] = *(const short8_t*)(&Bsh[(wc * 32 + ni * 16 + c) * 32 + g * 8]);
      bl[ni] = *(const short8_t*)(&Bsl[(wc * 32 + ni * 16 + c) * 32 + g * 8]);
    }
#pragma unroll
    for (int mi = 0; mi < 4; ++mi)
#pragma unroll
      for (int ni = 0; ni < 2; ++ni) {
        acc[mi][ni] = __builtin_amdgcn_mfma_f32_16x16x32_bf16(
            a[mi], bh[ni], acc[mi][ni], 0, 0, 0);
        acc[mi][ni] = __builtin_amdgcn_mfma_f32_16x16x32_bf16(
            a[mi], bl[ni], acc[mi][ni], 0, 0, 0);
      }
    __syncthreads();
  }

  // D layout: col = lane&15, row = (lane>>4)*4 + reg
#pragma unroll
  for (int mi = 0; mi < 4; ++mi) {
#pragma unroll
    for (int ni = 0; ni < 2; ++ni) {
      int col = n0 + wc * 32 + ni * 16 + c;
      int hh = col >> 6, dd = col & 63;
      if (EPI == 2) {
        int row0 = m0 + wr * 64 + mi * 16 + g * 4;
        int bb = row0 >> 11, ss0 = row0 & 2047;
        short4_t s4;
#pragma unroll
        for (int j = 0; j < 4; ++j) s4[j] = (short)f32_to_bf16(acc[mi][ni][j]);
        *(short4_t*)(&Ohi[(((size_t)bb * HEADS + hh) * DK + dd) * SEQ + ss0]) = s4;
      } else {
#pragma unroll
        for (int j = 0; j < 4; ++j) {
          int row = m0 + wr * 64 + mi * 16 + g * 4 + j;
          int bb = row >> 11, ss = row & 2047;
          size_t idx = (((size_t)bb * HEADS + hh) * SEQ + ss) * DK + dd;
          float x = acc[mi][ni][j];
          unsigned short xh = f32_to_bf16(x);
          Ohi[idx] = (short)xh;
          if (EPI == 0)
            Olo[idx] = (short)f32_to_bf16(x - bf16_to_f32(xh));
        }
      }
    }
  }
}

// ---------------------------------------------------------------------------
// Output GEMM: O[M,1024] fp32 = A[M,K] @ Bw[1024,K]^T, plain bf16, 1 chain.
// Tile 128M x 64N.
// ---------------------------------------------------------------------------
__global__ __launch_bounds__(256, 2) void gemm_out(
    const short* __restrict__ A, const short* __restrict__ Bw,
    float* __restrict__ O, int M, int K) {
  __shared__ short As[128 * 32];
  __shared__ short Bs[64 * 32];

  const int tid = threadIdx.x;
  const int w = tid >> 6, l = tid & 63, g = l >> 4, c = l & 15;
  const int wr = w >> 1, wc = w & 1;
  const int m0 = blockIdx.y * 128, n0 = blockIdx.x * 64;

  f32x4_t acc[4][2] = {};

  for (int k0 = 0; k0 < K; k0 += 32) {
#pragma unroll
    for (int j = 0; j < 2; ++j) {
      int e = (w * 2 + j) * 512 + l * 8;
      int r = e >> 5, cc = e & 31;
      gload_lds16(A + (size_t)(m0 + r) * K + k0 + cc, &As[(w * 2 + j) * 512]);
    }
    {
      int e = w * 512 + l * 8;
      int r = e >> 5, cc = e & 31;
      gload_lds16(Bw + (size_t)(n0 + r) * K + k0 + cc, &Bs[w * 512]);
    }
    __syncthreads();

    short8_t a[4], b[2];
#pragma unroll
    for (int mi = 0; mi < 4; ++mi)
      a[mi] = *(const short8_t*)(&As[(wr * 64 + mi * 16 + c) * 32 + g * 8]);
#pragma unroll
    for (int ni = 0; ni < 2; ++ni)
      b[ni] = *(const short8_t*)(&Bs[(wc * 32 + ni * 16 + c) * 32 + g * 8]);
#pragma unroll
    for (int mi = 0; mi < 4; ++mi)
#pragma unroll
      for (int ni = 0; ni < 2; ++ni)
        acc[mi][ni] = __builtin_amdgcn_mfma_f32_16x16x32_bf16(
            a[mi], b[ni], acc[mi][ni], 0, 0, 0);
    __syncthreads();
  }

#pragma unroll
  for (int mi = 0; mi < 4; ++mi)
#pragma unroll
    for (int ni = 0; ni < 2; ++ni) {
      int col = n0 + wc * 32 + ni * 16 + c;
#pragma unroll
      for (int j = 0; j < 4; ++j) {
        int row = m0 + wr * 64 + mi * 16 + g * 4 + j;
        O[(size_t)row * DFF + col] = acc[mi][ni][j];
      }
    }
}

// ---------------------------------------------------------------------------
// Flash attention v4. Grid: (B*H, S/128). Block 256 = 4 waves x 32 q-rows.
// S^T: mfma(A=K_hi rows kv, B=Q_{hi,lo} rows q) -> D[row=kv][col=q], 2 chains.
// PV: O^T = mfma(A=V^T rows d, B=P rows q).
// K_hi + V^T staged in LDS (stride-72 pad); issue-early K/V prefetch; mask
// register prefetch (loads for chunk t+1 issued right after t's are consumed).
// ---------------------------------------------------------------------------
__global__ __launch_bounds__(256, 2) void attn_kernel(
    const short* __restrict__ qhh, const short* __restrict__ qhl,
    const short* __restrict__ khh, const short* __restrict__ vt,
    const float* __restrict__ mask, short* __restrict__ ctx) {
  const int bh = blockIdx.x;
  const int b = bh >> 4;
  const int h = bh & 15;
  const int qt = blockIdx.y;
  const int tid = threadIdx.x;
  const int w = tid >> 6, l = tid & 63, g = l >> 4, c = l & 15;

  __shared__ short Khs[64 * 72];      // K chunk hi [kv][k], stride 72
  __shared__ short Vts[64 * 72];      // V^T chunk [d][kv], stride 72
  __shared__ short Ps[4][32 * 72];    // per-wave P tile [q][kv]
  short* psw = &Ps[w][0];

  const int qrow0 = qt * 128 + w * 32;
  const short* Qbh = qhh + ((size_t)bh * SEQ + qrow0) * DK;
  const short* Qbl = qhl + ((size_t)bh * SEQ + qrow0) * DK;
  const short* Kbh = khh + (size_t)bh * SEQ * DK;
  const short* Vb  = vt  + (size_t)bh * DK * SEQ;           // [64][SEQ]
  const float* M0  = mask + (size_t)b * SEQ * SEQ + (size_t)(qrow0 + c) * SEQ;

  // staging: each thread copies 16 contiguous shorts per buffer
  const int srow = tid >> 2;            // 0..63
  const int scol = (tid & 3) * 16;      // 0,16,32,48
  const int sofs = srow * 72 + scol;

  // Q frags (B-operand): lane c holds Q row q=mi*16+c, k = ks*32+g*8
  short8_t qfh[2][2], qfl[2][2];
#pragma unroll
  for (int mi = 0; mi < 2; ++mi)
#pragma unroll
    for (int ks = 0; ks < 2; ++ks) {
      qfh[mi][ks] = *(const short8_t*)(Qbh + (size_t)(mi * 16 + c) * DK + ks * 32 + g * 8);
      qfl[mi][ks] = *(const short8_t*)(Qbl + (size_t)(mi * 16 + c) * DK + ks * 32 + g * 8);
    }

  // prologue: chunk-0 staging regs + chunk-0 mask regs
  short8_t rkh0 = *(const short8_t*)(Kbh + (size_t)srow * DK + scol);
  short8_t rkh1 = *(const short8_t*)(Kbh + (size_t)srow * DK + scol + 8);
  short8_t rv0  = *(const short8_t*)(Vb  + (size_t)srow * SEQ + scol);
  short8_t rv1  = *(const short8_t*)(Vb  + (size_t)srow * SEQ + scol + 8);
  float4 mpre[2][4];
#pragma unroll
  for (int mi = 0; mi < 2; ++mi)
#pragma unroll
    for (int ni = 0; ni < 4; ++ni)
      mpre[mi][ni] = *(const float4*)(M0 + (size_t)(mi * 16) * SEQ + ni * 16 + g * 4);

  f32x4_t o[4][2] = {};          // o[di][mi]: O^T rows d=di*16+g*4+j, col q
  float mrun[2] = {-1e30f, -1e30f};
  float lrun[2] = {0.f, 0.f};

  for (int kv0 = 0; kv0 < SEQ; kv0 += 64) {
    __syncthreads();             // prev iter's readers done
    *(short8_t*)(&Khs[sofs]) = rkh0;
    *(short8_t*)(&Khs[sofs + 8]) = rkh1;
    *(short8_t*)(&Vts[sofs]) = rv0;
    *(short8_t*)(&Vts[sofs + 8]) = rv1;
    __syncthreads();             // staged data visible to all waves

    const int kv1 = kv0 + 64;
    // issue-early: next chunk's K/V loads overlap this iteration's compute
    if (kv1 < SEQ) {
      rkh0 = *(const short8_t*)(Kbh + (size_t)(kv1 + srow) * DK + scol);
      rkh1 = *(const short8_t*)(Kbh + (size_t)(kv1 + srow) * DK + scol + 8);
      rv0  = *(const short8_t*)(Vb  + (size_t)srow * SEQ + kv1 + scol);
      rv1  = *(const short8_t*)(Vb  + (size_t)srow * SEQ + kv1 + scol + 8);
    }

    // ---- S^T = K_hi (Q_hi + Q_lo)^T : 2 chains, K frags from LDS ----
    f32x4_t sa[4][2] = {};       // sa[ni][mi]: rows kv=ni*16+g*4+j, col q
#pragma unroll
    for (int ks = 0; ks < 2; ++ks) {
      short8_t ah[4];
#pragma unroll
      for (int ni = 0; ni < 4; ++ni)
        ah[ni] = *(const short8_t*)(&Khs[(ni * 16 + c) * 72 + ks * 32 + g * 8]);
#pragma unroll
      for (int ni = 0; ni < 4; ++ni)
#pragma unroll
        for (int mi = 0; mi < 2; ++mi) {
          sa[ni][mi] = __builtin_amdgcn_mfma_f32_16x16x32_bf16(
              ah[ni], qfh[mi][ks], sa[ni][mi], 0, 0, 0);
          sa[ni][mi] = __builtin_amdgcn_mfma_f32_16x16x32_bf16(
              ah[ni], qfl[mi][ks], sa[ni][mi], 0, 0, 0);
        }
    }

    // ---- + additive mask from prefetched regs; then prefetch t+1 ----
#pragma unroll
    for (int mi = 0; mi < 2; ++mi)
#pragma unroll
      for (int ni = 0; ni < 4; ++ni) {
        sa[ni][mi][0] += mpre[mi][ni].x;
        sa[ni][mi][1] += mpre[mi][ni].y;
        sa[ni][mi][2] += mpre[mi][ni].z;
        sa[ni][mi][3] += mpre[mi][ni].w;
      }
    if (kv1 < SEQ) {
#pragma unroll
      for (int mi = 0; mi < 2; ++mi)
#pragma unroll
        for (int ni = 0; ni < 4; ++ni)
          mpre[mi][ni] = *(const float4*)(M0 + (size_t)(mi * 16) * SEQ + kv1 + ni * 16 + g * 4);
    }

    // ---- online softmax: one (m,l) per q-col (per mi) ----
#pragma unroll
    for (int mi = 0; mi < 2; ++mi) {
      float t = sa[0][mi][0];
#pragma unroll
      for (int ni = 0; ni < 4; ++ni)
#pragma unroll
        for (int j = 0; j < 4; ++j) t = fmaxf(t, sa[ni][mi][j]);
      t = fmaxf(t, __shfl_xor(t, 16));
      t = fmaxf(t, __shfl_xor(t, 32));
      float mold = mrun[mi];
      float mnew = fmaxf(mold, t);
      float sc = __expf(mold - mnew);
      mrun[mi] = mnew;
#pragma unroll
      for (int di = 0; di < 4; ++di)
#pragma unroll
        for (int j = 0; j < 4; ++j) o[di][mi][j] *= sc;
      float psum = 0.f;
#pragma unroll
      for (int ni = 0; ni < 4; ++ni) {
        short4_t ph;
#pragma unroll
        for (int j = 0; j < 4; ++j) {
          float p = __expf(sa[ni][mi][j] - mnew);
          psum += p;
          ph[j] = (short)f32_to_bf16(p);
        }
        // P store: [q][kv] A-layout, b64, conflict-free
        *(short4_t*)(&psw[(mi * 16 + c) * 72 + ni * 16 + g * 4]) = ph;
      }
      lrun[mi] = lrun[mi] * sc + psum;
    }

    // ---- O^T += V^T P^T : V frags from LDS ----
#pragma unroll
    for (int ks = 0; ks < 2; ++ks) {
      short8_t pb[2];
#pragma unroll
      for (int mi = 0; mi < 2; ++mi)
        pb[mi] = *(const short8_t*)(&psw[(mi * 16 + c) * 72 + ks * 32 + g * 8]);
#pragma unroll
      for (int di = 0; di < 4; ++di) {
        short8_t av = *(const short8_t*)(&Vts[(di * 16 + c) * 72 + ks * 32 + g * 8]);
#pragma unroll
        for (int mi = 0; mi < 2; ++mi)
          o[di][mi] = __builtin_amdgcn_mfma_f32_16x16x32_bf16(
              av, pb[mi], o[di][mi], 0, 0, 0);
      }
    }
  }

  // ---- finalize: reduce l across g-groups, normalize, short4 stores ----
  float inv[2];
#pragma unroll
  for (int mi = 0; mi < 2; ++mi) {
    float s = lrun[mi];
    s += __shfl_xor(s, 16);
    s += __shfl_xor(s, 32);
    inv[mi] = 1.f / s;
  }
  short* Cb = ctx + ((size_t)b * SEQ + qrow0) * DFF + h * DK;
#pragma unroll
  for (int mi = 0; mi < 2; ++mi)
#pragma unroll
    for (int di = 0; di < 4; ++di) {
      short4_t s4;
#pragma unroll
      for (int j = 0; j < 4; ++j)
        s4[j] = (short)f32_to_bf16(o[di][mi][j] * inv[mi]);
      *(short4_t*)(Cb + (size_t)(mi * 16 + c) * DFF + di * 16 + g * 4) = s4;
    }
}

// ---------------------------------------------------------------------------
extern "C" void kernel_launch(void* const* d_in, const int* in_sizes, int n_in,
                              void* d_out, int out_size, void* d_ws, size_t ws_size,
                              hipStream_t stream) {
  const float* q    = (const float*)d_in[0];
  const float* k    = (const float*)d_in[1];
  const float* v    = (const float*)d_in[2];
  const float* mask = (const float*)d_in[3];
  const float* Wq   = (const float*)d_in[4];
  const float* Wk   = (const float*)d_in[5];
  const float* Wv   = (const float*)d_in[6];
  const float* Wo   = (const float*)d_in[7];
  float* out = (float*)d_out;

  const size_t NQ = 4194304;   // 4096*1024
  const size_t NW = 1048576;   // 1024*1024
  short* ws   = (short*)d_ws;
  short* qbf  = ws;            // A0; reused as kh_h after Q-proj
  short* kbf  = ws + NQ;       // A1; reused as vtp after K-proj
  short* vbf  = ws + 2 * NQ;   // A2; reused as ctx after V-proj
  short* qh_h = ws + 3 * NQ;
  short* qh_l = ws + 4 * NQ;
  short* wbase = ws + 5 * NQ;  // [wq_h wq_l wk_h wk_l wv_h wv_l wob], NW each
  short* wq_h = wbase;
  short* wq_l = wbase + NW;
  short* wk_h = wbase + 2 * NW;
  short* wk_l = wbase + 3 * NW;
  short* wv_h = wbase + 4 * NW;
  short* wv_l = wbase + 5 * NW;
  short* wob  = wbase + 6 * NW;   // total 5*NQ + 7*NW = 56.6 MB

  short* kh_h = qbf;   // aliases (stream-ordered, safe)
  short* vtp  = kbf;   // V transposed [B,H,64,S]
  short* ctx  = vbf;

  cvt_x_kernel<<<dim3(4096, 3), 256, 0, stream>>>(q, k, v, ws, (int)NQ);
  cvt_w_kernel<<<dim3(1024, 4), 256, 0, stream>>>(Wq, Wk, Wv, Wo, wbase, (int)NW);

  dim3 gg(16, 32);   // N/64, M/128
  gemm_proj<0><<<gg, 256, 0, stream>>>(qbf, wq_h, wq_l, qh_h, qh_l, 4096, 1024);
  gemm_proj<1><<<gg, 256, 0, stream>>>(kbf, wk_h, wk_l, kh_h, nullptr, 4096, 1024);
  gemm_proj<2><<<gg, 256, 0, stream>>>(vbf, wv_h, wv_l, vtp, nullptr, 4096, 1024);

  attn_kernel<<<dim3(32, 16), 256, 0, stream>>>(qh_h, qh_l, kh_h, vtp, mask, ctx);

  gemm_out<<<gg, 256, 0, stream>>>(ctx, wob, out, 4096, 1024);
}

// Round 7
// 203.096 us; speedup vs baseline: 1.8974x; 1.0402x over previous
//
#include <hip/hip_runtime.h>
#include <hip/hip_bf16.h>

// ---------------------------------------------------------------------------
// T5 MHA: B=2, S=2048, D_FF=1024, H=16, DK=64, INNER=1024
// Precision: q carried hi+lo (2-chain QK vs k_hi); W's split for projections.
// Attn v5: 512-thr blocks (8 waves x 16 q-rows) -> 4 waves/SIMD, 2 blocks/CU.
//          S^T layout, K-hi + V^T LDS staging, issue-early K/V prefetch,
//          mask register prefetch, setprio around MFMA clusters.
// ---------------------------------------------------------------------------

typedef __attribute__((ext_vector_type(8))) short short8_t;   // 8 bf16 (4 VGPR)
typedef __attribute__((ext_vector_type(4))) short short4_t;
typedef __attribute__((ext_vector_type(4))) float f32x4_t;

#define SEQ 2048
#define HEADS 16
#define DK 64
#define DFF 1024

__device__ __forceinline__ unsigned short f32_to_bf16(float f) {
  unsigned int u = __float_as_uint(f);
  u += 0x7FFFu + ((u >> 16) & 1u);   // round-to-nearest-even
  return (unsigned short)(u >> 16);
}
__device__ __forceinline__ float bf16_to_f32(unsigned short h) {
  return __uint_as_float(((unsigned int)h) << 16);
}

__device__ __forceinline__ void gload_lds16(const void* g, void* l) {
  __builtin_amdgcn_global_load_lds(
      (__attribute__((address_space(1))) void*)(g),
      (__attribute__((address_space(3))) void*)(l), 16, 0, 0);
}

// ---------------------------------------------------------------------------
// cvt_x: q/k/v fp32 -> bf16, one dispatch (blockIdx.y selects tensor)
// ---------------------------------------------------------------------------
__global__ void cvt_x_kernel(const float* __restrict__ q,
                             const float* __restrict__ k,
                             const float* __restrict__ v,
                             short* __restrict__ dst, int n) {
  const float* src = (blockIdx.y == 0) ? q : (blockIdx.y == 1) ? k : v;
  short* out = dst + (size_t)blockIdx.y * n;
  int i = (blockIdx.x * 256 + threadIdx.x) * 4;
  if (i >= n) return;
  float4 f = *(const float4*)(src + i);
  short4_t s;
  s[0] = (short)f32_to_bf16(f.x);
  s[1] = (short)f32_to_bf16(f.y);
  s[2] = (short)f32_to_bf16(f.z);
  s[3] = (short)f32_to_bf16(f.w);
  *(short4_t*)(out + i) = s;
}

// ---------------------------------------------------------------------------
// cvt_w: y<3 -> split W[y] into hi+lo pair; y==3 -> plain Wo
// ---------------------------------------------------------------------------
__global__ void cvt_w_kernel(const float* __restrict__ Wq,
                             const float* __restrict__ Wk,
                             const float* __restrict__ Wv,
                             const float* __restrict__ Wo,
                             short* __restrict__ wbase, int n) {
  int y = blockIdx.y;
  const float* src = (y == 0) ? Wq : (y == 1) ? Wk : (y == 2) ? Wv : Wo;
  int i = (blockIdx.x * 256 + threadIdx.x) * 4;
  if (i >= n) return;
  float4 f = *(const float4*)(src + i);
  float ff[4] = {f.x, f.y, f.z, f.w};
  if (y < 3) {
    short* hi = wbase + (size_t)(2 * y) * n;
    short* lo = wbase + (size_t)(2 * y + 1) * n;
    short4_t h, l;
#pragma unroll
    for (int j = 0; j < 4; ++j) {
      unsigned short hh = f32_to_bf16(ff[j]);
      h[j] = (short)hh;
      l[j] = (short)f32_to_bf16(ff[j] - bf16_to_f32(hh));
    }
    *(short4_t*)(hi + i) = h;
    *(short4_t*)(lo + i) = l;
  } else {
    short* out = wbase + (size_t)6 * n;
    short4_t s;
#pragma unroll
    for (int j = 0; j < 4; ++j) s[j] = (short)f32_to_bf16(ff[j]);
    *(short4_t*)(out + i) = s;
  }
}

// ---------------------------------------------------------------------------
// Projection GEMM: C[M,1024] = A[M,K] @ (Bh+Bl)[1024,K]^T, 2 MFMA chains.
// Tile 128M x 64N, BK=32, 256 thr (4 waves 2x2; per wave 64x32 = 4x2 frags).
// EPI 0: bf16 hi+lo head-split (Q); EPI 1: hi head-split (K);
// EPI 2: hi TRANSPOSED [B,H,64,S] (V)
// ---------------------------------------------------------------------------
template <int EPI>
__global__ __launch_bounds__(256, 2) void gemm_proj(
    const short* __restrict__ A, const short* __restrict__ Bh,
    const short* __restrict__ Bl, short* __restrict__ Ohi,
    short* __restrict__ Olo, int M, int K) {
  __shared__ short As[128 * 32];
  __shared__ short Bsh[64 * 32];
  __shared__ short Bsl[64 * 32];

  const int tid = threadIdx.x;
  const int w = tid >> 6, l = tid & 63, g = l >> 4, c = l & 15;
  const int wr = w >> 1, wc = w & 1;
  const int m0 = blockIdx.y * 128, n0 = blockIdx.x * 64;

  f32x4_t acc[4][2] = {};

  for (int k0 = 0; k0 < K; k0 += 32) {
#pragma unroll
    for (int j = 0; j < 2; ++j) {
      int e = (w * 2 + j) * 512 + l * 8;
      int r = e >> 5, cc = e & 31;
      gload_lds16(A + (size_t)(m0 + r) * K + k0 + cc, &As[(w * 2 + j) * 512]);
    }
    {
      int e = w * 512 + l * 8;
      int r = e >> 5, cc = e & 31;
      gload_lds16(Bh + (size_t)(n0 + r) * K + k0 + cc, &Bsh[w * 512]);
      gload_lds16(Bl + (size_t)(n0 + r) * K + k0 + cc, &Bsl[w * 512]);
    }
    __syncthreads();

    short8_t a[4], bh[2], bl[2];
#pragma unroll
    for (int mi = 0; mi < 4; ++mi)
      a[mi] = *(const short8_t*)(&As[(wr * 64 + mi * 16 + c) * 32 + g * 8]);
#pragma unroll
    for (int ni = 0; ni < 2; ++ni) {
      bh[ni] = *(const short8_t*)(&Bsh[(wc * 32 + ni * 16 + c) * 32 + g * 8]);
      bl[ni] = *(const short8_t*)(&Bsl[(wc * 32 + ni * 16 + c) * 32 + g * 8]);
    }
#pragma unroll
    for (int mi = 0; mi < 4; ++mi)
#pragma unroll
      for (int ni = 0; ni < 2; ++ni) {
        acc[mi][ni] = __builtin_amdgcn_mfma_f32_16x16x32_bf16(
            a[mi], bh[ni], acc[mi][ni], 0, 0, 0);
        acc[mi][ni] = __builtin_amdgcn_mfma_f32_16x16x32_bf16(
            a[mi], bl[ni], acc[mi][ni], 0, 0, 0);
      }
    __syncthreads();
  }

  // D layout: col = lane&15, row = (lane>>4)*4 + reg
#pragma unroll
  for (int mi = 0; mi < 4; ++mi) {
#pragma unroll
    for (int ni = 0; ni < 2; ++ni) {
      int col = n0 + wc * 32 + ni * 16 + c;
      int hh = col >> 6, dd = col & 63;
      if (EPI == 2) {
        int row0 = m0 + wr * 64 + mi * 16 + g * 4;
        int bb = row0 >> 11, ss0 = row0 & 2047;
        short4_t s4;
#pragma unroll
        for (int j = 0; j < 4; ++j) s4[j] = (short)f32_to_bf16(acc[mi][ni][j]);
        *(short4_t*)(&Ohi[(((size_t)bb * HEADS + hh) * DK + dd) * SEQ + ss0]) = s4;
      } else {
#pragma unroll
        for (int j = 0; j < 4; ++j) {
          int row = m0 + wr * 64 + mi * 16 + g * 4 + j;
          int bb = row >> 11, ss = row & 2047;
          size_t idx = (((size_t)bb * HEADS + hh) * SEQ + ss) * DK + dd;
          float x = acc[mi][ni][j];
          unsigned short xh = f32_to_bf16(x);
          Ohi[idx] = (short)xh;
          if (EPI == 0)
            Olo[idx] = (short)f32_to_bf16(x - bf16_to_f32(xh));
        }
      }
    }
  }
}

// ---------------------------------------------------------------------------
// Output GEMM: O[M,1024] fp32 = A[M,K] @ Bw[1024,K]^T, plain bf16, 1 chain.
// ---------------------------------------------------------------------------
__global__ __launch_bounds__(256, 2) void gemm_out(
    const short* __restrict__ A, const short* __restrict__ Bw,
    float* __restrict__ O, int M, int K) {
  __shared__ short As[128 * 32];
  __shared__ short Bs[64 * 32];

  const int tid = threadIdx.x;
  const int w = tid >> 6, l = tid & 63, g = l >> 4, c = l & 15;
  const int wr = w >> 1, wc = w & 1;
  const int m0 = blockIdx.y * 128, n0 = blockIdx.x * 64;

  f32x4_t acc[4][2] = {};

  for (int k0 = 0; k0 < K; k0 += 32) {
#pragma unroll
    for (int j = 0; j < 2; ++j) {
      int e = (w * 2 + j) * 512 + l * 8;
      int r = e >> 5, cc = e & 31;
      gload_lds16(A + (size_t)(m0 + r) * K + k0 + cc, &As[(w * 2 + j) * 512]);
    }
    {
      int e = w * 512 + l * 8;
      int r = e >> 5, cc = e & 31;
      gload_lds16(Bw + (size_t)(n0 + r) * K + k0 + cc, &Bs[w * 512]);
    }
    __syncthreads();

    short8_t a[4], b[2];
#pragma unroll
    for (int mi = 0; mi < 4; ++mi)
      a[mi] = *(const short8_t*)(&As[(wr * 64 + mi * 16 + c) * 32 + g * 8]);
#pragma unroll
    for (int ni = 0; ni < 2; ++ni)
      b[ni] = *(const short8_t*)(&Bs[(wc * 32 + ni * 16 + c) * 32 + g * 8]);
#pragma unroll
    for (int mi = 0; mi < 4; ++mi)
#pragma unroll
      for (int ni = 0; ni < 2; ++ni)
        acc[mi][ni] = __builtin_amdgcn_mfma_f32_16x16x32_bf16(
            a[mi], b[ni], acc[mi][ni], 0, 0, 0);
    __syncthreads();
  }

#pragma unroll
  for (int mi = 0; mi < 4; ++mi)
#pragma unroll
    for (int ni = 0; ni < 2; ++ni) {
      int col = n0 + wc * 32 + ni * 16 + c;
#pragma unroll
      for (int j = 0; j < 4; ++j) {
        int row = m0 + wr * 64 + mi * 16 + g * 4 + j;
        O[(size_t)row * DFF + col] = acc[mi][ni][j];
      }
    }
}

// ---------------------------------------------------------------------------
// Flash attention v5. Grid: (B*H, S/128). Block 512 = 8 waves x 16 q-rows.
// 2 blocks/CU -> 4 waves/SIMD. S^T: mfma(A=K_hi rows kv, B=Q rows q).
// PV: O^T = mfma(A=V^T rows d, B=P rows q). K_hi + V^T staged in LDS
// (stride-72); issue-early K/V prefetch; mask register prefetch.
// ---------------------------------------------------------------------------
__global__ __launch_bounds__(512, 4) void attn_kernel(
    const short* __restrict__ qhh, const short* __restrict__ qhl,
    const short* __restrict__ khh, const short* __restrict__ vt,
    const float* __restrict__ mask, short* __restrict__ ctx) {
  const int bh = blockIdx.x;
  const int b = bh >> 4;
  const int h = bh & 15;
  const int qt = blockIdx.y;
  const int tid = threadIdx.x;
  const int w = tid >> 6, l = tid & 63, g = l >> 4, c = l & 15;

  __shared__ short Khs[64 * 72];      // K chunk hi [kv][k], stride 72
  __shared__ short Vts[64 * 72];      // V^T chunk [d][kv], stride 72
  __shared__ short Ps[8][16 * 72];    // per-wave P tile [q=16][kv], stride 72
  short* psw = &Ps[w][0];

  const int qrow0 = qt * 128 + w * 16;
  const short* Qbh = qhh + ((size_t)bh * SEQ + qrow0) * DK;
  const short* Qbl = qhl + ((size_t)bh * SEQ + qrow0) * DK;
  const short* Kbh = khh + (size_t)bh * SEQ * DK;
  const short* Vb  = vt  + (size_t)bh * DK * SEQ;           // [64][SEQ]
  const float* M0  = mask + (size_t)b * SEQ * SEQ + (size_t)(qrow0 + c) * SEQ;

  // staging: 512 threads x 1 short8 per buffer = full 64x64 coverage
  const int srow = tid >> 3;            // 0..63
  const int scol = (tid & 7) * 8;       // 0..56
  const int sofs = srow * 72 + scol;

  // Q frags (B-operand): lane c holds Q row q=c, k = ks*32+g*8
  short8_t qfh[2], qfl[2];
#pragma unroll
  for (int ks = 0; ks < 2; ++ks) {
    qfh[ks] = *(const short8_t*)(Qbh + (size_t)c * DK + ks * 32 + g * 8);
    qfl[ks] = *(const short8_t*)(Qbl + (size_t)c * DK + ks * 32 + g * 8);
  }

  // prologue: chunk-0 staging regs + chunk-0 mask regs
  short8_t rkh = *(const short8_t*)(Kbh + (size_t)srow * DK + scol);
  short8_t rv  = *(const short8_t*)(Vb  + (size_t)srow * SEQ + scol);
  float4 mpre[4];
#pragma unroll
  for (int ni = 0; ni < 4; ++ni)
    mpre[ni] = *(const float4*)(M0 + ni * 16 + g * 4);

  f32x4_t o[4] = {};             // o[di]: O^T rows d=di*16+g*4+j, col q=c
  float mrun = -1e30f;
  float lrun = 0.f;

  for (int kv0 = 0; kv0 < SEQ; kv0 += 64) {
    __syncthreads();             // prev iter's readers done
    *(short8_t*)(&Khs[sofs]) = rkh;
    *(short8_t*)(&Vts[sofs]) = rv;
    __syncthreads();             // staged data visible to all waves

    const int kv1 = kv0 + 64;
    // issue-early: next chunk's K/V loads overlap this iteration's compute
    if (kv1 < SEQ) {
      rkh = *(const short8_t*)(Kbh + (size_t)(kv1 + srow) * DK + scol);
      rv  = *(const short8_t*)(Vb  + (size_t)srow * SEQ + kv1 + scol);
    }

    // ---- S^T = K_hi (Q_hi + Q_lo)^T : 2 chains, K frags from LDS ----
    f32x4_t sa[4] = {};          // sa[ni]: rows kv=ni*16+g*4+j, col q=c
    __builtin_amdgcn_s_setprio(1);
#pragma unroll
    for (int ks = 0; ks < 2; ++ks) {
      short8_t ah[4];
#pragma unroll
      for (int ni = 0; ni < 4; ++ni)
        ah[ni] = *(const short8_t*)(&Khs[(ni * 16 + c) * 72 + ks * 32 + g * 8]);
#pragma unroll
      for (int ni = 0; ni < 4; ++ni) {
        sa[ni] = __builtin_amdgcn_mfma_f32_16x16x32_bf16(
            ah[ni], qfh[ks], sa[ni], 0, 0, 0);
        sa[ni] = __builtin_amdgcn_mfma_f32_16x16x32_bf16(
            ah[ni], qfl[ks], sa[ni], 0, 0, 0);
      }
    }
    __builtin_amdgcn_s_setprio(0);

    // ---- + additive mask from prefetched regs; then prefetch t+1 ----
#pragma unroll
    for (int ni = 0; ni < 4; ++ni) {
      sa[ni][0] += mpre[ni].x;
      sa[ni][1] += mpre[ni].y;
      sa[ni][2] += mpre[ni].z;
      sa[ni][3] += mpre[ni].w;
    }
    if (kv1 < SEQ) {
#pragma unroll
      for (int ni = 0; ni < 4; ++ni)
        mpre[ni] = *(const float4*)(M0 + kv1 + ni * 16 + g * 4);
    }

    // ---- online softmax: one (m,l) per q-col ----
    {
      float t = sa[0][0];
#pragma unroll
      for (int ni = 0; ni < 4; ++ni)
#pragma unroll
        for (int j = 0; j < 4; ++j) t = fmaxf(t, sa[ni][j]);
      t = fmaxf(t, __shfl_xor(t, 16));
      t = fmaxf(t, __shfl_xor(t, 32));
      float mold = mrun;
      float mnew = fmaxf(mold, t);
      float sc = __expf(mold - mnew);
      mrun = mnew;
#pragma unroll
      for (int di = 0; di < 4; ++di)
#pragma unroll
        for (int j = 0; j < 4; ++j) o[di][j] *= sc;
      float psum = 0.f;
#pragma unroll
      for (int ni = 0; ni < 4; ++ni) {
        short4_t ph;
#pragma unroll
        for (int j = 0; j < 4; ++j) {
          float p = __expf(sa[ni][j] - mnew);
          psum += p;
          ph[j] = (short)f32_to_bf16(p);
        }
        // P store: [q][kv] A-layout, b64, 2-way max (free)
        *(short4_t*)(&psw[c * 72 + ni * 16 + g * 4]) = ph;
      }
      lrun = lrun * sc + psum;
    }

    // ---- O^T += V^T P^T : V frags from LDS ----
    __builtin_amdgcn_s_setprio(1);
#pragma unroll
    for (int ks = 0; ks < 2; ++ks) {
      short8_t pb = *(const short8_t*)(&psw[c * 72 + ks * 32 + g * 8]);
#pragma unroll
      for (int di = 0; di < 4; ++di) {
        short8_t av = *(const short8_t*)(&Vts[(di * 16 + c) * 72 + ks * 32 + g * 8]);
        o[di] = __builtin_amdgcn_mfma_f32_16x16x32_bf16(
            av, pb, o[di], 0, 0, 0);
      }
    }
    __builtin_amdgcn_s_setprio(0);
  }

  // ---- finalize: reduce l across g-groups, normalize, short4 stores ----
  float s = lrun;
  s += __shfl_xor(s, 16);
  s += __shfl_xor(s, 32);
  float inv = 1.f / s;
  short* Cb = ctx + ((size_t)b * SEQ + qrow0) * DFF + h * DK;
#pragma unroll
  for (int di = 0; di < 4; ++di) {
    short4_t s4;
#pragma unroll
    for (int j = 0; j < 4; ++j)
      s4[j] = (short)f32_to_bf16(o[di][j] * inv);
    *(short4_t*)(Cb + (size_t)c * DFF + di * 16 + g * 4) = s4;
  }
}

// ---------------------------------------------------------------------------
extern "C" void kernel_launch(void* const* d_in, const int* in_sizes, int n_in,
                              void* d_out, int out_size, void* d_ws, size_t ws_size,
                              hipStream_t stream) {
  const float* q    = (const float*)d_in[0];
  const float* k    = (const float*)d_in[1];
  const float* v    = (const float*)d_in[2];
  const float* mask = (const float*)d_in[3];
  const float* Wq   = (const float*)d_in[4];
  const float* Wk   = (const float*)d_in[5];
  const float* Wv   = (const float*)d_in[6];
  const float* Wo   = (const float*)d_in[7];
  float* out = (float*)d_out;

  const size_t NQ = 4194304;   // 4096*1024
  const size_t NW = 1048576;   // 1024*1024
  short* ws   = (short*)d_ws;
  short* qbf  = ws;            // A0; reused as kh_h after Q-proj
  short* kbf  = ws + NQ;       // A1; reused as vtp after K-proj
  short* vbf  = ws + 2 * NQ;   // A2; reused as ctx after V-proj
  short* qh_h = ws + 3 * NQ;
  short* qh_l = ws + 4 * NQ;
  short* wbase = ws + 5 * NQ;  // [wq_h wq_l wk_h wk_l wv_h wv_l wob], NW each
  short* wq_h = wbase;
  short* wq_l = wbase + NW;
  short* wk_h = wbase + 2 * NW;
  short* wk_l = wbase + 3 * NW;
  short* wv_h = wbase + 4 * NW;
  short* wv_l = wbase + 5 * NW;
  short* wob  = wbase + 6 * NW;   // total 5*NQ + 7*NW = 56.6 MB

  short* kh_h = qbf;   // aliases (stream-ordered, safe)
  short* vtp  = kbf;   // V transposed [B,H,64,S]
  short* ctx  = vbf;

  cvt_x_kernel<<<dim3(4096, 3), 256, 0, stream>>>(q, k, v, ws, (int)NQ);
  cvt_w_kernel<<<dim3(1024, 4), 256, 0, stream>>>(Wq, Wk, Wv, Wo, wbase, (int)NW);

  dim3 gg(16, 32);   // N/64, M/128
  gemm_proj<0><<<gg, 256, 0, stream>>>(qbf, wq_h, wq_l, qh_h, qh_l, 4096, 1024);
  gemm_proj<1><<<gg, 256, 0, stream>>>(kbf, wk_h, wk_l, kh_h, nullptr, 4096, 1024);
  gemm_proj<2><<<gg, 256, 0, stream>>>(vbf, wv_h, wv_l, vtp, nullptr, 4096, 1024);

  attn_kernel<<<dim3(32, 16), 512, 0, stream>>>(qh_h, qh_l, kh_h, vtp, mask, ctx);

  gemm_out<<<gg, 256, 0, stream>>>(ctx, wob, out, 4096, 1024);
}